// Round 2
// baseline (945.013 us; speedup 1.0000x reference)
//
#include <hip/hip_runtime.h>

#define NRES 1024
#define CM 256
#define CZ 128
#define LN_EPS 1e-5f

typedef float f32x4 __attribute__((ext_vector_type(4)));

__device__ __forceinline__ f32x4 ld4(const float* p) {
    return *reinterpret_cast<const f32x4*>(p);
}

// m layernorm: one 64-lane wave per row of 256 (float4/lane), 4 rows/block.
__global__ __launch_bounds__(256) void m_ln_kernel(
    const float* __restrict__ m, const float* __restrict__ w,
    const float* __restrict__ b, float* __restrict__ out)
{
    const int row  = blockIdx.x * 4 + (threadIdx.x >> 6);
    const int lane = threadIdx.x & 63;
    const f32x4 v = ld4(m + (size_t)row * CM + lane * 4);
    float s  = v.x + v.y + v.z + v.w;
    float s2 = v.x*v.x + v.y*v.y + v.z*v.z + v.w*v.w;
    #pragma unroll
    for (int off = 1; off < 64; off <<= 1) {
        s  += __shfl_xor(s,  off);
        s2 += __shfl_xor(s2, off);
    }
    const float mu  = s * (1.0f / CM);
    const float var = s2 * (1.0f / CM) - mu * mu;
    const float inv = rsqrtf(var + LN_EPS);
    const f32x4 wv = ld4(w + lane * 4);
    const f32x4 bv = ld4(b + lane * 4);
    f32x4 o;
    o.x = (v.x - mu) * inv * wv.x + bv.x;
    o.y = (v.y - mu) * inv * wv.y + bv.y;
    o.z = (v.z - mu) * inv * wv.z + bv.z;
    o.w = (v.w - mu) * inv * wv.w + bv.w;
    *reinterpret_cast<f32x4*>(out + (size_t)row * CM + lane * 4) = o;
}

// z layernorm + distogram add: 32 lanes per row of 128 (float4/lane),
// 8 rows per 256-thread block, grid-stride over 131072 row-groups.
__global__ __launch_bounds__(256) void z_kernel(
    const float* __restrict__ z, const float* __restrict__ x,
    const float* __restrict__ w, const float* __restrict__ b,
    const float* __restrict__ lw, const float* __restrict__ lb,
    float* __restrict__ out)
{
    const int lane32 = threadIdx.x & 31;
    const int sub    = threadIdx.x >> 5;   // 0..7: row within group
    const int c0     = lane32 * 4;

    // row-invariant per-channel params (all L1-resident)
    const f32x4 wv  = ld4(w  + c0);
    const f32x4 bv  = ld4(b  + c0);
    const f32x4 lbv = ld4(lb + c0);

    // sq_bins: bins = 3.25 + 1.25*k (exact in fp32), squared (exact)
    const float sq[15] = {
        10.5625f, 20.25f, 33.0625f, 49.0f, 68.0625f, 90.25f, 115.5625f,
        144.0f, 175.5625f, 210.25f, 248.0625f, 289.0f, 333.0625f,
        380.25f, 430.5625f
    };

    const int ngroups = (NRES * NRES) / 8;
    for (int g = blockIdx.x; g < ngroups; g += gridDim.x) {
        const int r = g * 8 + sub;
        const int i = r >> 10;
        const int j = r & (NRES - 1);

        // squared pairwise distance (x is 12 KB, fully cached)
        const float dx = x[i*3+0] - x[j*3+0];
        const float dy = x[i*3+1] - x[j*3+1];
        const float dz = x[i*3+2] - x[j*3+2];
        const float d2 = dx*dx + dy*dy + dz*dz;

        // one-hot bin: strict (d2 > sq[k]) && (d2 < upper[k]); may be none.
        int bin = -1;
        #pragma unroll
        for (int k = 0; k < 15; ++k) {
            const float up = (k < 14) ? sq[k + 1] : 1e8f;
            if (d2 > sq[k] && d2 < up) bin = k;
        }

        f32x4 add;
        if (bin >= 0) {
            // lin_w is [C_Z=128, NUM_BINS=15], 7.7 KB — L1-resident gather
            add.x = lw[(c0 + 0) * 15 + bin];
            add.y = lw[(c0 + 1) * 15 + bin];
            add.z = lw[(c0 + 2) * 15 + bin];
            add.w = lw[(c0 + 3) * 15 + bin];
        } else {
            add.x = add.y = add.z = add.w = 0.0f;
        }

        const size_t base = (size_t)r * CZ + c0;
        const f32x4 v = __builtin_nontemporal_load(
            reinterpret_cast<const f32x4*>(z + base));

        float s  = v.x + v.y + v.z + v.w;
        float s2 = v.x*v.x + v.y*v.y + v.z*v.z + v.w*v.w;
        #pragma unroll
        for (int off = 1; off < 32; off <<= 1) {
            s  += __shfl_xor(s,  off, 32);
            s2 += __shfl_xor(s2, off, 32);
        }
        const float mu  = s * (1.0f / CZ);
        const float var = s2 * (1.0f / CZ) - mu * mu;
        const float inv = rsqrtf(var + LN_EPS);

        f32x4 o;
        o.x = (v.x - mu) * inv * wv.x + bv.x + add.x + lbv.x;
        o.y = (v.y - mu) * inv * wv.y + bv.y + add.y + lbv.y;
        o.z = (v.z - mu) * inv * wv.z + bv.z + add.z + lbv.z;
        o.w = (v.w - mu) * inv * wv.w + bv.w + add.w + lbv.w;
        __builtin_nontemporal_store(o, reinterpret_cast<f32x4*>(out + base));
    }
}

extern "C" void kernel_launch(void* const* d_in, const int* in_sizes, int n_in,
                              void* d_out, int out_size, void* d_ws, size_t ws_size,
                              hipStream_t stream) {
    const float* m    = (const float*)d_in[0];
    const float* z    = (const float*)d_in[1];
    const float* x    = (const float*)d_in[2];
    const float* lnmw = (const float*)d_in[3];
    const float* lnmb = (const float*)d_in[4];
    const float* lnzw = (const float*)d_in[5];
    const float* lnzb = (const float*)d_in[6];
    const float* linw = (const float*)d_in[7];
    const float* linb = (const float*)d_in[8];
    float* out = (float*)d_out;

    float* out_m = out;                       // [1024, 256]
    float* out_z = out + (size_t)NRES * CM;   // [1024, 1024, 128]

    // m: 1024 rows, 4 rows/block -> 256 blocks
    m_ln_kernel<<<NRES / 4, 256, 0, stream>>>(m, lnmw, lnmb, out_m);

    // z: 1M rows, 8 rows/block-iter, grid-stride at 2048 blocks
    z_kernel<<<2048, 256, 0, stream>>>(z, x, lnzw, lnzb, linw, linb, out_z);
}